// Round 13
// baseline (86.461 us; speedup 1.0000x reference)
//
#include <hip/hip_runtime.h>

// LSTM cell, B=4096, D=H=1024.
//   X = [inputs | h_prev]  (4096 x 2048) bf16   (ws, 16 MB)
//   Wct[g][h][k] = concat(W_g,U_g)^T bf16       (ws, 16 MB)
//   8-phase 256x256 fused GEMM (4 gates x 64 h per block) + LSTM epilogue.
//   R13 = R12 minus s_setprio around MFMA clusters (T5 is negative on
//   lockstep single-barrier-group schedules, m190). Everything else is the
//   verified R12: 16x16x32 MFMA, conflict-free XOR swizzle, XCD-locality
//   block map, fused single-launch prep.

typedef __attribute__((ext_vector_type(8))) short bfrag8;   // 8 bf16 (4 VGPRs)

__device__ __forceinline__ unsigned int f2bf(float f) {
  unsigned int u = __builtin_bit_cast(unsigned int, f);
  unsigned int r = (u + 0x7fffu + ((u >> 16) & 1u)) >> 16;
  return r & 0xffffu;
}

// ------------- fused prep: X cast/concat + W transpose/cast ------------------
__global__ __launch_bounds__(256) void prep_all(
    const float* __restrict__ inputs, const float* __restrict__ h_prev,
    const float* __restrict__ s0, const float* __restrict__ s1,
    const float* __restrict__ s2, const float* __restrict__ s3,
    const float* __restrict__ s4, const float* __restrict__ s5,
    const float* __restrict__ s6, const float* __restrict__ s7,
    unsigned short* __restrict__ X, unsigned short* __restrict__ Wct) {
  const int bidAll = blockIdx.x;
  const int tid = threadIdx.x;
  if (bidAll < 4096) {
    int idx = bidAll * 256 + tid;
    int b  = idx >> 8;
    int k8 = (idx & 255) * 8;
    const float* src = (k8 < 1024) ? (inputs + (size_t)b * 1024 + k8)
                                   : (h_prev + (size_t)b * 1024 + (k8 - 1024));
    float4 v0 = ((const float4*)src)[0];
    float4 v1 = ((const float4*)src)[1];
    uint4 o;
    o.x = f2bf(v0.x) | (f2bf(v0.y) << 16);
    o.y = f2bf(v0.z) | (f2bf(v0.w) << 16);
    o.z = f2bf(v1.x) | (f2bf(v1.y) << 16);
    o.w = f2bf(v1.z) | (f2bf(v1.w) << 16);
    *(uint4*)(X + (size_t)b * 2048 + k8) = o;
    return;
  }
  int blk = bidAll - 4096;
  int m = blk >> 8;
  const float* src = (m == 0) ? s0 : (m == 1) ? s1 : (m == 2) ? s2 : (m == 3) ? s3
                   : (m == 4) ? s4 : (m == 5) ? s5 : (m == 6) ? s6 : s7;
  int g = m >> 1, half = m & 1;
  unsigned short* dst = Wct + (size_t)g * 1024 * 2048 + (size_t)half * 1024;
  int t = blk & 255;
  int k0 = (t >> 4) * 64;
  int h0 = (t & 15) * 64;
  __shared__ float lt[64][68];
  #pragma unroll
  for (int it = 0; it < 4; ++it) {
    int r  = (tid >> 4) + it * 16;
    int c4 = (tid & 15) * 4;
    float4 v = *(const float4*)(src + (size_t)(k0 + r) * 1024 + h0 + c4);
    lt[r][c4 + 0] = v.x; lt[r][c4 + 1] = v.y; lt[r][c4 + 2] = v.z; lt[r][c4 + 3] = v.w;
  }
  __syncthreads();
  #pragma unroll
  for (int it = 0; it < 4; ++it) {
    int hh  = (tid >> 4) + it * 16;
    int kk4 = (tid & 15) * 4;
    uint2 o;
    o.x = f2bf(lt[kk4 + 0][hh]) | (f2bf(lt[kk4 + 1][hh]) << 16);
    o.y = f2bf(lt[kk4 + 2][hh]) | (f2bf(lt[kk4 + 3][hh]) << 16);
    *(uint2*)(dst + (size_t)(h0 + hh) * 2048 + k0 + kk4) = o;
  }
}

// ---------------- 8-phase fused 4-gate GEMM + LSTM epilogue ------------------

#define FENCE() asm volatile("" ::: "memory")
#define BARRIER() do { FENCE(); __builtin_amdgcn_s_barrier(); FENCE(); } while (0)
#define VMCNT(n) asm volatile("s_waitcnt vmcnt(" #n ")" ::: "memory")
#define LGKM(n) asm volatile("s_waitcnt lgkmcnt(" #n ")" ::: "memory")
#define GLOAD16(gp, lp) __builtin_amdgcn_global_load_lds( \
    (const __attribute__((address_space(1))) unsigned int*)(gp), \
    (__attribute__((address_space(3))) unsigned int*)(lp), 16, 0, 0)
#define DSR(dst, addr, off) asm volatile("ds_read_b128 %0, %1 offset:%c2" \
    : "=v"(dst) : "v"(addr), "n"(off))

// full AGPR clobber list (keeps the allocator out of a0-a127)
#define AC "a0","a1","a2","a3","a4","a5","a6","a7","a8","a9","a10","a11","a12","a13","a14","a15", \
 "a16","a17","a18","a19","a20","a21","a22","a23","a24","a25","a26","a27","a28","a29","a30","a31", \
 "a32","a33","a34","a35","a36","a37","a38","a39","a40","a41","a42","a43","a44","a45","a46","a47", \
 "a48","a49","a50","a51","a52","a53","a54","a55","a56","a57","a58","a59","a60","a61","a62","a63", \
 "a64","a65","a66","a67","a68","a69","a70","a71","a72","a73","a74","a75","a76","a77","a78","a79", \
 "a80","a81","a82","a83","a84","a85","a86","a87","a88","a89","a90","a91","a92","a93","a94","a95", \
 "a96","a97","a98","a99","a100","a101","a102","a103","a104","a105","a106","a107","a108","a109","a110","a111", \
 "a112","a113","a114","a115","a116","a117","a118","a119","a120","a121","a122","a123","a124","a125","a126","a127"

#define WZ(n) "v_accvgpr_write_b32 a" #n ", 0\n\t"
#define AINIT() asm volatile( \
 WZ(0)WZ(1)WZ(2)WZ(3)WZ(4)WZ(5)WZ(6)WZ(7)WZ(8)WZ(9)WZ(10)WZ(11)WZ(12)WZ(13)WZ(14)WZ(15) \
 WZ(16)WZ(17)WZ(18)WZ(19)WZ(20)WZ(21)WZ(22)WZ(23)WZ(24)WZ(25)WZ(26)WZ(27)WZ(28)WZ(29)WZ(30)WZ(31) \
 WZ(32)WZ(33)WZ(34)WZ(35)WZ(36)WZ(37)WZ(38)WZ(39)WZ(40)WZ(41)WZ(42)WZ(43)WZ(44)WZ(45)WZ(46)WZ(47) \
 WZ(48)WZ(49)WZ(50)WZ(51)WZ(52)WZ(53)WZ(54)WZ(55)WZ(56)WZ(57)WZ(58)WZ(59)WZ(60)WZ(61)WZ(62)WZ(63) \
 WZ(64)WZ(65)WZ(66)WZ(67)WZ(68)WZ(69)WZ(70)WZ(71)WZ(72)WZ(73)WZ(74)WZ(75)WZ(76)WZ(77)WZ(78)WZ(79) \
 WZ(80)WZ(81)WZ(82)WZ(83)WZ(84)WZ(85)WZ(86)WZ(87)WZ(88)WZ(89)WZ(90)WZ(91)WZ(92)WZ(93)WZ(94)WZ(95) \
 WZ(96)WZ(97)WZ(98)WZ(99)WZ(100)WZ(101)WZ(102)WZ(103)WZ(104)WZ(105)WZ(106)WZ(107)WZ(108)WZ(109)WZ(110)WZ(111) \
 WZ(112)WZ(113)WZ(114)WZ(115)WZ(116)WZ(117)WZ(118)WZ(119)WZ(120)WZ(121)WZ(122)WZ(123)WZ(124)WZ(125)WZ(126)WZ(127) \
 ::: AC)

#define MFMA_ONE(BR, AF, BF) asm volatile( \
    "v_mfma_f32_16x16x32_bf16 a[" BR "], %0, %1, a[" BR "]" \
    :: "v"(AF), "v"(BF) : AC)

// 16 MFMA: acc[g][MH*4+mi] += A4[mi] * B4[g]; bases (g*8+MH*4+mi)*4
// R13: no setprio (T5 negative on lockstep schedules, m190)
#define CLUSTER16(A4, B4, R00,R01,R02,R03, R10,R11,R12,R13, R20,R21,R22,R23, R30,R31,R32,R33) do { \
  MFMA_ONE(R00, (A4)[0], (B4)[0]); MFMA_ONE(R01, (A4)[1], (B4)[0]); \
  MFMA_ONE(R02, (A4)[2], (B4)[0]); MFMA_ONE(R03, (A4)[3], (B4)[0]); \
  MFMA_ONE(R10, (A4)[0], (B4)[1]); MFMA_ONE(R11, (A4)[1], (B4)[1]); \
  MFMA_ONE(R12, (A4)[2], (B4)[1]); MFMA_ONE(R13, (A4)[3], (B4)[1]); \
  MFMA_ONE(R20, (A4)[0], (B4)[2]); MFMA_ONE(R21, (A4)[1], (B4)[2]); \
  MFMA_ONE(R22, (A4)[2], (B4)[2]); MFMA_ONE(R23, (A4)[3], (B4)[2]); \
  MFMA_ONE(R30, (A4)[0], (B4)[3]); MFMA_ONE(R31, (A4)[1], (B4)[3]); \
  MFMA_ONE(R32, (A4)[2], (B4)[3]); MFMA_ONE(R33, (A4)[3], (B4)[3]); \
} while (0)

#define CL_MH0(A4, B4) CLUSTER16(A4, B4, \
  "0:3","4:7","8:11","12:15", "32:35","36:39","40:43","44:47", \
  "64:67","68:71","72:75","76:79", "96:99","100:103","104:107","108:111")
#define CL_MH1(A4, B4) CLUSTER16(A4, B4, \
  "16:19","20:23","24:27","28:31", "48:51","52:55","56:59","60:63", \
  "80:83","84:87","88:91","92:95", "112:115","116:119","120:123","124:127")

// reads: A frag (mh, mi, kk) at row (wm*128+mh*64+mi*16+u), byte row*128+sw(kk)
#define READ_A4(arr, BUF, MH, ABASE) do { \
  DSR(arr[0], ABASE, (BUF)*32768 + (MH)*8192 + 0);    \
  DSR(arr[1], ABASE, (BUF)*32768 + (MH)*8192 + 2048); \
  DSR(arr[2], ABASE, (BUF)*32768 + (MH)*8192 + 4096); \
  DSR(arr[3], ABASE, (BUF)*32768 + (MH)*8192 + 6144); \
} while (0)

#define READ_B4N(arr, BUF, BBASE) do { \
  DSR(arr[0], BBASE, (BUF)*32768 + 0);    \
  DSR(arr[1], BBASE, (BUF)*32768 + 2048); \
  DSR(arr[2], BBASE, (BUF)*32768 + 4096); \
  DSR(arr[3], BBASE, (BUF)*32768 + 6144); \
} while (0)

#define STAGE_A(BUF, H, kt) do { int _kb = ((kt) < 32 ? (kt) : 31) * 64; \
  GLOAD16(pA0 + (size_t)(H) * 262144 + _kb, smem + (BUF)*32768 + (H)*16384 + stbase); \
  GLOAD16(pA1 + (size_t)(H) * 262144 + _kb, smem + (BUF)*32768 + (H)*16384 + stbase + 1024); \
} while (0)

#define STAGE_B(BUF, kt) do { int _kb = ((kt) < 32 ? (kt) : 31) * 64; \
  GLOAD16(pB00 + _kb, smem + 65536 + (BUF)*32768 + stbase); \
  GLOAD16(pB01 + _kb, smem + 65536 + (BUF)*32768 + stbase + 1024); \
  GLOAD16(pB10 + _kb, smem + 65536 + (BUF)*32768 + 16384 + stbase); \
  GLOAD16(pB11 + _kb, smem + 65536 + (BUF)*32768 + 16384 + stbase + 1024); \
} while (0)

#define ARD(X, RS) asm volatile("v_accvgpr_read_b32 %0, " RS : "=v"(X))

#define EPI_M(Mi, F0,F1,F2,F3, I0,I1,I2,I3, C0,C1,C2,C3, O0,O1,O2,O3) do { \
  float pf[4], pi[4], pc[4], po[4]; \
  ARD(pf[0],F0); ARD(pf[1],F1); ARD(pf[2],F2); ARD(pf[3],F3); \
  ARD(pi[0],I0); ARD(pi[1],I1); ARD(pi[2],I2); ARD(pi[3],I3); \
  ARD(pc[0],C0); ARD(pc[1],C1); ARD(pc[2],C2); ARD(pc[3],C3); \
  ARD(po[0],O0); ARD(po[1],O1); ARD(po[2],O2); ARD(po[3],O3); \
  _Pragma("unroll") for (int j = 0; j < 4; ++j) { \
    const int b = rbw + (Mi) * 16 + q * 4 + j; \
    float xf = pf[j] + Bgf, xi = pi[j] + Bgi, xc = pc[j] + Bgc, xo = po[j] + Bgo; \
    float fg = 1.f / (1.f + __expf(-xf)); \
    float ig = 1.f / (1.f + __expf(-xi)); \
    float ct = 2.f / (1.f + __expf(-2.f * xc)) - 1.f; \
    float og = 1.f / (1.f + __expf(-xo)); \
    float cn = fg * c_prev[(size_t)b * 1024 + hcol] + ig * ct; \
    float hn = og * (2.f / (1.f + __expf(-2.f * cn)) - 1.f); \
    out[(size_t)b * 1024 + hcol] = hn; \
    out[(size_t)4194304 + (size_t)b * 1024 + hcol] = cn; \
  } \
} while (0)

__global__ __launch_bounds__(512, 2) void lstm_gemm(
    const unsigned short* __restrict__ X, const unsigned short* __restrict__ Wct,
    const float* __restrict__ c_prev,
    const float* __restrict__ bfv, const float* __restrict__ biv,
    const float* __restrict__ bcv, const float* __restrict__ bov,
    float* __restrict__ out) {
  extern __shared__ __align__(16) char smem[];
  const int tid = threadIdx.x;
  const int lane = tid & 63, w = tid >> 6;
  const int u = lane & 15, q = (lane >> 4) & 3;
  const int wm = w >> 2, wn = w & 3;

  // XCD-locality swizzle: XCD (bid&7) -> 128-h slab x 16 M-tiles
  const int bid = blockIdx.x;
  const int xcd = bid & 7, idx = bid >> 3;
  const int row0 = (idx & 15) * 256;
  const int h0 = (xcd * 2 + (idx >> 4)) * 64;

  const unsigned lds0 = (unsigned)(size_t)((__attribute__((address_space(3))) char*)smem);

  // fragment read bases: sw(kk) = ((kk*4+q) ^ (u&7)) << 4
  const int sw0 = (q ^ (u & 7)) << 4;
  const int sw1 = ((q + 4) ^ (u & 7)) << 4;
  const unsigned aA0 = lds0 + wm * 16384 + u * 128 + sw0;           // A, kk0
  const unsigned aA1 = lds0 + wm * 16384 + u * 128 + sw1;           // A, kk1
  const unsigned aB0 = lds0 + 65536 + (wn * 64 + u) * 128 + sw0;    // B, kk0
  const unsigned aB1 = lds0 + 65536 + (wn * 64 + u) * 128 + sw1;    // B, kk1

  // staging: wave w covers chunk rows w*16..w*16+15; linear dest, pre-swz src
  const int stbase = w * 2048 + lane * 16;
  const int rA0 = w * 16 + (lane >> 3), rA1 = rA0 + 8;
  const int ssA = (lane & 7) ^ (rA0 & 7);
  const unsigned short* pA0 = X + (size_t)(row0 + rA0) * 2048 + ssA * 8;
  const unsigned short* pA1 = X + (size_t)(row0 + rA1) * 2048 + ssA * 8;
  auto wrow = [&](int C) { return (((C >> 4) & 3) << 10) + h0 + ((C >> 6) << 4) + (C & 15); };
  const unsigned short* pB00 = Wct + (size_t)wrow(rA0) * 2048 + ssA * 8;
  const unsigned short* pB01 = Wct + (size_t)wrow(rA1) * 2048 + ssA * 8;
  const unsigned short* pB10 = Wct + (size_t)wrow(128 + rA0) * 2048 + ssA * 8;
  const unsigned short* pB11 = Wct + (size_t)wrow(128 + rA1) * 2048 + ssA * 8;

  AINIT();

  bfrag8 Ab0[4], Ab1[4], Bb0[4], Bb1[4];

  // prologue: stage even KT (buf0) + B-odd (buf1); read PH1's frags
  STAGE_A(0, 0, 0); STAGE_A(0, 1, 0);    // Ae (4)
  STAGE_B(0, 0);                          // Be (4)
  STAGE_B(1, 1);                          // Bo (4) stays in flight
  VMCNT(4);
  BARRIER();
  READ_A4(Ab0, 0, 0, aA0);                // A[mh0,e,kk0]
  READ_B4N(Bb0, 0, aB0);                  // B[e,kk0]

  #pragma unroll 1
  for (int t = 0; t < 16; ++t) {
    const int kt1 = 2 * t + 1, kt2 = 2 * t + 2, kt3 = 2 * t + 3;
    // PH1: cluster(e,kk0,mh0) | read A[mh1,e,kk0] | stage Ao
    READ_A4(Ab1, 0, 1, aA0);
    STAGE_A(1, 0, kt1); STAGE_A(1, 1, kt1);
    BARRIER(); LGKM(4);
    CL_MH0(Ab0, Bb0);
    // PH2: cluster(e,kk0,mh1) | read A[mh0,e,kk1] + B[e,kk1]
    READ_A4(Ab0, 0, 0, aA1);
    READ_B4N(Bb1, 0, aB1);
    BARRIER(); LGKM(8);
    CL_MH1(Ab1, Bb0);
    // PH3: cluster(e,kk1,mh0) | read A[mh1,e,kk1] | drain odd staging
    READ_A4(Ab1, 0, 1, aA1);
    VMCNT(0);
    BARRIER(); LGKM(4);
    CL_MH0(Ab0, Bb1);
    // PH4: cluster(e,kk1,mh1) | read A[mh0,o,kk0] + B[o,kk0] | stage Be'
    READ_A4(Ab0, 1, 0, aA0);
    READ_B4N(Bb0, 1, aB0);
    STAGE_B(0, kt2);
    BARRIER(); LGKM(8);
    CL_MH1(Ab1, Bb1);
    // PH5: cluster(o,kk0,mh0) | read A[mh1,o,kk0] | stage Ae'
    READ_A4(Ab1, 1, 1, aA0);
    STAGE_A(0, 0, kt2); STAGE_A(0, 1, kt2);
    BARRIER(); LGKM(4);
    CL_MH0(Ab0, Bb0);
    // PH6: cluster(o,kk0,mh1) | read A[mh0,o,kk1] + B[o,kk1]
    READ_A4(Ab0, 1, 0, aA1);
    READ_B4N(Bb1, 1, aB1);
    BARRIER(); LGKM(8);
    CL_MH1(Ab1, Bb0);
    // PH7: cluster(o,kk1,mh0) | read A[mh1,o,kk1] | drain even staging
    READ_A4(Ab1, 1, 1, aA1);
    VMCNT(0);
    BARRIER(); LGKM(4);
    CL_MH0(Ab0, Bb1);
    // PH8: cluster(o,kk1,mh1) | read A[mh0,e',kk0] + B[e',kk0] | stage Bo'
    READ_A4(Ab0, 0, 0, aA0);
    READ_B4N(Bb0, 0, aB0);
    STAGE_B(1, kt3);
    BARRIER(); LGKM(8);
    CL_MH1(Ab1, Bb1);
  }
  VMCNT(0); LGKM(0);
  asm volatile("s_nop 7\n\ts_nop 7");   // MFMA -> accvgpr_read hazard guard

  const int hcol = h0 + wn * 16 + u;
  const float Bgf = bfv[hcol], Bgi = biv[hcol], Bgc = bcv[hcol], Bgo = bov[hcol];
  const int rbw = row0 + wm * 128;
  EPI_M(0, "a0","a1","a2","a3",     "a32","a33","a34","a35",
           "a64","a65","a66","a67", "a96","a97","a98","a99");
  EPI_M(1, "a4","a5","a6","a7",     "a36","a37","a38","a39",
           "a68","a69","a70","a71", "a100","a101","a102","a103");
  EPI_M(2, "a8","a9","a10","a11",   "a40","a41","a42","a43",
           "a72","a73","a74","a75", "a104","a105","a106","a107");
  EPI_M(3, "a12","a13","a14","a15", "a44","a45","a46","a47",
           "a76","a77","a78","a79", "a108","a109","a110","a111");
  EPI_M(4, "a16","a17","a18","a19", "a48","a49","a50","a51",
           "a80","a81","a82","a83", "a112","a113","a114","a115");
  EPI_M(5, "a20","a21","a22","a23", "a52","a53","a54","a55",
           "a84","a85","a86","a87", "a116","a117","a118","a119");
  EPI_M(6, "a24","a25","a26","a27", "a56","a57","a58","a59",
           "a88","a89","a90","a91", "a120","a121","a122","a123");
  EPI_M(7, "a28","a29","a30","a31", "a60","a61","a62","a63",
           "a92","a93","a94","a95", "a124","a125","a126","a127");
}

extern "C" void kernel_launch(void* const* d_in, const int* in_sizes, int n_in,
                              void* d_out, int out_size, void* d_ws, size_t ws_size,
                              hipStream_t stream) {
  const float* inputs = (const float*)d_in[0];
  const float* h_prev = (const float*)d_in[1];
  const float* c_prev = (const float*)d_in[2];
  const float* Wf = (const float*)d_in[3];
  const float* Uf = (const float*)d_in[4];
  const float* bf = (const float*)d_in[5];
  const float* Wi = (const float*)d_in[6];
  const float* Ui = (const float*)d_in[7];
  const float* bi = (const float*)d_in[8];
  const float* Wc = (const float*)d_in[9];
  const float* Uc = (const float*)d_in[10];
  const float* bc = (const float*)d_in[11];
  const float* Wo = (const float*)d_in[12];
  const float* Uo = (const float*)d_in[13];
  const float* bo = (const float*)d_in[14];
  float* out = (float*)d_out;

  unsigned short* X   = (unsigned short*)d_ws;                 // 16 MB
  unsigned short* Wct = X + (size_t)4096 * 2048;               // 16 MB

  (void)hipFuncSetAttribute(reinterpret_cast<const void*>(lstm_gemm),
                            hipFuncAttributeMaxDynamicSharedMemorySize, 131072);

  prep_all<<<6144, 256, 0, stream>>>(inputs, h_prev,
                                     Wf, Uf, Wi, Ui, Wc, Uc, Wo, Uo, X, Wct);
  lstm_gemm<<<256, 512, 131072, stream>>>(X, Wct, c_prev, bf, bi, bc, bo, out);
}